// Round 16
// baseline (194.165 us; speedup 1.0000x reference)
//
#include <hip/hip_runtime.h>
#include <stdint.h>

typedef __attribute__((ext_vector_type(8))) short short8;
typedef __attribute__((ext_vector_type(4))) float f32x4;

typedef const unsigned int __attribute__((address_space(1))) gu32;
typedef unsigned int __attribute__((address_space(3))) lu32;

__device__ __forceinline__ float bf2f(unsigned short u) {
  union { unsigned int i; float f; } v; v.i = ((unsigned int)u) << 16; return v.f;
}
__device__ __forceinline__ unsigned short f2bf(float f) {
  union { float f; unsigned int i; } v; v.f = f;
  unsigned int r = v.i + 0x7FFFu + ((v.i >> 16) & 1u);
  return (unsigned short)(r >> 16);
}
__device__ __forceinline__ float fexp2(float x) {
  float r; asm("v_exp_f32 %0, %1" : "=v"(r) : "v"(x)); return r;
}
__device__ __forceinline__ unsigned int cvtpk(float lo, float hi) {
  unsigned int r;
  asm("v_cvt_pk_bf16_f32 %0, %1, %2" : "=v"(r) : "v"(lo), "v"(hi));
  return r;
}

// ------- fused: cast X fp32->bf16 (blocks 0..8191) + fold LoRA (8192..) ---
__global__ __launch_bounds__(256) void prep_in(
    const float* __restrict__ X, unsigned short* __restrict__ Xb,
    const float* __restrict__ Wq, const float* __restrict__ Wk,
    const float* __restrict__ Wv, const float* __restrict__ Wo,
    const float* __restrict__ qd, const float* __restrict__ qu,
    const float* __restrict__ kd, const float* __restrict__ ku,
    const float* __restrict__ vd, const float* __restrict__ vu,
    const float* __restrict__ od, const float* __restrict__ ou,
    unsigned short* __restrict__ Wqkv, unsigned short* __restrict__ Wob)
{
  if (blockIdx.x < 8192) {
    int i = (blockIdx.x * 256 + threadIdx.x) * 4;
    float4 v = *(const float4*)&X[i];
    unsigned long long pk = (unsigned long long)f2bf(v.x) |
                            ((unsigned long long)f2bf(v.y) << 16) |
                            ((unsigned long long)f2bf(v.z) << 32) |
                            ((unsigned long long)f2bf(v.w) << 48);
    *(unsigned long long*)&Xb[i] = pk;
    return;
  }
  int idx = (blockIdx.x - 8192) * 256 + threadIdx.x;
  int sel = idx >> 18;
  int rem = (idx & 0x3FFFF) * 4;
  int o = rem >> 10, c = rem & 1023;
  const float *W, *up, *dn;
  if (sel == 0)      { W = Wq; up = qu; dn = qd; }
  else if (sel == 1) { W = Wk; up = ku; dn = kd; }
  else if (sel == 2) { W = Wv; up = vu; dn = vd; }
  else               { W = Wo; up = ou; dn = od; }
  float4 wv = *(const float4*)&W[rem];
  float a0 = wv.x, a1 = wv.y, a2 = wv.z, a3 = wv.w;
  #pragma unroll
  for (int r = 0; r < 4; r++) {
    float u = up[o * 4 + r];
    float4 dv = *(const float4*)&dn[r * 1024 + c];
    a0 += u * dv.x; a1 += u * dv.y; a2 += u * dv.z; a3 += u * dv.w;
  }
  unsigned long long pk = (unsigned long long)f2bf(a0) |
                          ((unsigned long long)f2bf(a1) << 16) |
                          ((unsigned long long)f2bf(a2) << 32) |
                          ((unsigned long long)f2bf(a3) << 48);
  if (sel < 3) *(unsigned long long*)&Wqkv[sel * 1048576 + rem] = pk;
  else         *(unsigned long long*)&Wob[rem] = pk;
}

// ---------------- bf16 GEMM, B^T input (C[m,n] = sum_k A[m,k]*B[n,k]) ----
// 128x128 tile, BK=32, 4 waves, 256 thr. 3-slot LDS rotation, counted
// vmcnt(4), vmcnt before barrier, lgkmcnt(0) read-pin. Grid x=m, y=n.
// OUTF=0 (QKV): LDS-repack epilogue, vbuf stride 148 shorts (296B == 10
// banks mod 32: g-groups at +8 banks -> 32 banks covered, 2 lanes/bank,
// conflict-free writes; Q/K reads 4-way max). Q -> QKV linear; K -> Kswz
// (16B-chunk XOR); V -> VTs transpose. OUTF=1: fp32+bias via LDS in two
// 64-row halves (stride 132 floats), full float4-coalesced stores.
template <int OUTF>
__global__ __launch_bounds__(256) void gemm_bt(
    const unsigned short* __restrict__ A, const unsigned short* __restrict__ B,
    unsigned short* __restrict__ Cb, float* __restrict__ Cf,
    const float* __restrict__ bias, unsigned short* __restrict__ Kswz,
    unsigned short* __restrict__ VTs, int M, int N, int K)
{
  __shared__ unsigned short sm[24576];          // 48KB: 3xA(12288) + 3xB(12288)
  unsigned short* smA = sm;                     // [3][128*32]
  unsigned short* smB = sm + 12288;             // [3][128*32]
  const int tid = threadIdx.x;
  const int w = tid >> 6, lane = tid & 63;
  const int g = lane >> 4, lr = lane & 15;
  const int m0 = blockIdx.x * 128, n0 = blockIdx.y * 128;   // x=m, y=n
  const int srow = lane >> 2;
  const int scol = (lane & 3) * 8;
  const unsigned short* gA = A + (size_t)(m0 + w * 16 + srow) * K + scol;
  const unsigned short* gB = B + (size_t)(n0 + w * 16 + srow) * K + scol;
  f32x4 acc[4][4] = {};
  const int wr = (w >> 1) * 64, wc = (w & 1) * 64;

  auto stage = [&](int buf, int k0) {
    #pragma unroll
    for (int i = 0; i < 2; i++) {
      __builtin_amdgcn_global_load_lds((gu32*)(gA + (size_t)i * 64 * K + k0),
          (lu32*)&smA[buf * 4096 + (i * 64 + w * 16) * 32], 16, 0, 0);
      __builtin_amdgcn_global_load_lds((gu32*)(gB + (size_t)i * 64 * K + k0),
          (lu32*)&smB[buf * 4096 + (i * 64 + w * 16) * 32], 16, 0, 0);
    }
  };
  auto compute = [&](int buf) {
    short8 a[4], b[4];
    #pragma unroll
    for (int mi = 0; mi < 4; mi++) a[mi] = *(const short8*)&smA[buf * 4096 + (wr + mi * 16 + lr) * 32 + g * 8];
    #pragma unroll
    for (int ni = 0; ni < 4; ni++) b[ni] = *(const short8*)&smB[buf * 4096 + (wc + ni * 16 + lr) * 32 + g * 8];
    #pragma unroll
    for (int mi = 0; mi < 4; mi++)
      #pragma unroll
      for (int ni = 0; ni < 4; ni++)
        acc[mi][ni] = __builtin_amdgcn_mfma_f32_16x16x32_bf16(a[mi], b[ni], acc[mi][ni], 0, 0, 0);
  };

  const int nt = K / 32;                 // >= 3
  stage(0, 0);
  stage(1, 32);
  int cur = 0;
  for (int t = 0; t + 2 < nt; ++t) {
    asm volatile("s_waitcnt vmcnt(4)" ::: "memory");   // stage(t) landed
    __builtin_amdgcn_sched_barrier(0);
    __builtin_amdgcn_s_barrier();
    __builtin_amdgcn_sched_barrier(0);
    int nb = (cur == 0) ? 2 : cur - 1;                 // (cur+2)%3
    stage(nb, (t + 2) * 32);
    compute(cur);
    asm volatile("s_waitcnt lgkmcnt(0)" ::: "memory"); // pin ds_reads before next barrier
    __builtin_amdgcn_sched_barrier(0);
    cur = (cur == 2) ? 0 : cur + 1;
  }
  asm volatile("s_waitcnt vmcnt(4)" ::: "memory");
  __builtin_amdgcn_sched_barrier(0);
  __builtin_amdgcn_s_barrier();
  __builtin_amdgcn_sched_barrier(0);
  compute(cur);
  asm volatile("s_waitcnt lgkmcnt(0)" ::: "memory");
  __builtin_amdgcn_sched_barrier(0);
  cur = (cur == 2) ? 0 : cur + 1;
  asm volatile("s_waitcnt vmcnt(0)" ::: "memory");     // all stages landed
  __builtin_amdgcn_sched_barrier(0);
  __builtin_amdgcn_s_barrier();
  __builtin_amdgcn_sched_barrier(0);
  compute(cur);

  if (OUTF == 1) {
    // fp32 + bias via LDS, two 64-row halves; full float4-coalesced stores
    float* fbuf = (float*)sm;                        // [64][132]: 33,792B
    #pragma unroll
    for (int h2 = 0; h2 < 2; h2++) {
      __syncthreads();
      if ((w >> 1) == h2) {
        #pragma unroll
        for (int mi = 0; mi < 4; mi++)
          #pragma unroll
          for (int ni = 0; ni < 4; ni++) {
            int col = n0 + wc + ni * 16 + lr;
            #pragma unroll
            for (int j = 0; j < 4; j++)
              fbuf[(mi * 16 + g * 4 + j) * 132 + wc + ni * 16 + lr] =
                  acc[mi][ni][j] + bias[col];
          }
      }
      __syncthreads();
      int r = tid >> 2, q = tid & 3;                 // 64 rows, 4 quarters
      float* dst = Cf + (size_t)(m0 + h2 * 64 + r) * N + n0 + q * 32;
      const float* src = &fbuf[r * 132 + q * 32];
      #pragma unroll
      for (int j = 0; j < 8; j++)
        *(float4*)&dst[j * 4] = *(const float4*)&src[j * 4];
    }
    return;
  }

  // ---- unified LDS-repack epilogue (all global_load_lds drained above) ----
  __syncthreads();                                   // all compute ds_reads done
  unsigned short* vbuf = sm;                         // [128][148]: 37,888B
  #pragma unroll
  for (int mi = 0; mi < 4; mi++)
    #pragma unroll
    for (int ni = 0; ni < 4; ni++)
      #pragma unroll
      for (int j = 0; j < 4; j++)
        vbuf[(wr + mi * 16 + g * 4 + j) * 148 + wc + ni * 16 + lr] =
            f2bf(acc[mi][ni][j]);
  __syncthreads();

  if (n0 < 1024) {
    // Q -> QKV rows (full 16B-coalesced)
    int r = tid >> 1, hf = tid & 1;
    unsigned short* dst = Cb + (size_t)(m0 + r) * 3072 + n0 + hf * 64;
    #pragma unroll
    for (int j = 0; j < 8; j++)
      *(short8*)&dst[j * 8] = *(const short8*)&vbuf[r * 148 + hf * 64 + j * 8];
  } else if (n0 < 2048) {
    // K -> Kswz: 16B-chunk XOR within the 128B row (d^((s&7)<<3) == chunk^sw)
    int r = tid >> 1, hf = tid & 1;
    int sg = m0 + r, b_ = sg >> 11, s = sg & 2047;
    int h = (n0 - 1024 + hf * 64) >> 6;
    size_t base = ((size_t)(b_ * 16 + h) * 2048 + s) * 64;
    int sw = s & 7;
    #pragma unroll
    for (int gch = 0; gch < 8; gch++)
      *(short8*)&Kswz[base + (gch ^ sw) * 8] =
          *(const short8*)&vbuf[r * 148 + hf * 64 + gch * 8];
  } else {
    // V -> VTs transpose (R14-proven algebra)
    int b_ = m0 >> 11, s0g = m0 & 2047;
    int ck0 = n0 - 2048;
    int dd = tid >> 1, shalf = tid & 1;              // dd: tile col 0..127
    int d = dd & 63, h = (ck0 >> 6) + (dd >> 6);
    size_t rowbase = ((size_t)(b_ * 16 + h) * 64 + d) * 2048;
    #pragma unroll
    for (int gp = 0; gp < 8; gp++) {
      int gs = gp ^ (d & 7);
      short8 o;
      #pragma unroll
      for (int j = 0; j < 8; j++)
        o[j] = (short)vbuf[(shalf * 64 + gs * 8 + j) * 148 + dd];
      *(short8*)&VTs[rowbase + s0g + shalf * 64 + gp * 8] = o;
    }
  }
}

// ---------------- flash attention, bf16, swapped QK^T (16x16) ------------
// grid: (64 bh, 8 q-blocks of 256); all q-blocks of one bh on one XCD.
__global__ __launch_bounds__(512, 4) void attn(
    const unsigned short* __restrict__ QKV,
    const unsigned short* __restrict__ Kswz,
    const unsigned short* __restrict__ VTs,
    unsigned short* __restrict__ O)
{
  __shared__ unsigned short smK[3][64 * 64];
  __shared__ unsigned short smV[3][64 * 64];
  __shared__ unsigned short smP[8][32 * 64];
  int bh = blockIdx.x, qb = blockIdx.y;
  int b = bh >> 4, h = bh & 15;
  int tid = threadIdx.x, w = tid >> 6, lane = tid & 63;
  int g = lane >> 4, lr = lane & 15;
  int q0 = qb * 256 + w * 32;
  const size_t kbse = (size_t)bh * 2048 * 64;
  const size_t vbse = (size_t)bh * 64 * 2048;
  const int srow8 = lane >> 3;
  const int sc8 = (lane & 7) * 8;

  auto stage = [&](int buf, int n0) {
    const unsigned short* gk = &Kswz[kbse + (size_t)(n0 + w * 8 + srow8) * 64 + sc8];
    __builtin_amdgcn_global_load_lds((gu32*)gk, (lu32*)&smK[buf][(w * 8) * 64], 16, 0, 0);
    const unsigned short* gv = &VTs[vbse + (size_t)(w * 8 + srow8) * 2048 + n0 + sc8];
    __builtin_amdgcn_global_load_lds((gu32*)gv, (lu32*)&smV[buf][(w * 8) * 64], 16, 0, 0);
  };

  const float SC = 0.125f * 1.44269504f;
  short8 bq[2][2];
  #pragma unroll
  for (int qf = 0; qf < 2; qf++)
    #pragma unroll
    for (int ks = 0; ks < 2; ks++) {
      short8 v = *(const short8*)&QKV[(size_t)(b * 2048 + q0 + qf * 16 + lr) * 3072 +
                                      h * 64 + ks * 32 + g * 8];
      #pragma unroll
      for (int j = 0; j < 4; j++) {
        float f0 = bf2f((unsigned short)v[2 * j]) * SC;
        float f1 = bf2f((unsigned short)v[2 * j + 1]) * SC;
        ((unsigned int*)&v)[j] = cvtpk(f0, f1);
      }
      bq[qf][ks] = v;
    }

  short8 vones;
  #pragma unroll
  for (int j = 0; j < 8; j++) vones[j] = (short)0x3F80;

  f32x4 acc_o[2][4] = {};
  f32x4 acc_l[2] = {};

  asm volatile("s_waitcnt vmcnt(0)" ::: "memory");
  __builtin_amdgcn_sched_barrier(0);
  stage(0, 0);
  stage(1, 64);

  auto compute = [&](int buf) {
    const unsigned short* K_ = smK[buf];
    const unsigned short* V_ = smV[buf];
    f32x4 s[4][2] = {};
    __builtin_amdgcn_s_setprio(1);
    #pragma unroll
    for (int nf = 0; nf < 4; nf++) {
      int row = nf * 16 + lr;
      #pragma unroll
      for (int ks = 0; ks < 2; ks++) {
        int eo = (ks * 64 + g * 16) ^ ((row & 7) << 4);
        short8 ak = *(const short8*)&K_[row * 64 + (eo >> 1)];
        #pragma unroll
        for (int qf = 0; qf < 2; qf++)
          s[nf][qf] = __builtin_amdgcn_mfma_f32_16x16x32_bf16(ak, bq[qf][ks], s[nf][qf], 0, 0, 0);
      }
    }
    __builtin_amdgcn_s_setprio(0);

    #pragma unroll
    for (int qf = 0; qf < 2; qf++) {
      int q = qf * 16 + lr;
      #pragma unroll
      for (int nf = 0; nf < 4; nf++) {
        float p0 = fexp2(s[nf][qf][0]);
        float p1 = fexp2(s[nf][qf][1]);
        float p2 = fexp2(s[nf][qf][2]);
        float p3 = fexp2(s[nf][qf][3]);
        uint2 pw;
        pw.x = cvtpk(p0, p1);
        pw.y = cvtpk(p2, p3);
        int eo = ((nf * 16 + g * 4) * 2) ^ ((q & 7) << 4);
        *(uint2*)&smP[w][q * 64 + (eo >> 1)] = pw;
      }
    }

    __builtin_amdgcn_s_setprio(1);
    #pragma unroll
    for (int ks = 0; ks < 2; ks++) {
      short8 ap[2];
      #pragma unroll
      for (int mq = 0; mq < 2; mq++) {
        int q = mq * 16 + lr;
        int eo = (ks * 64 + g * 16) ^ ((q & 7) << 4);
        ap[mq] = *(const short8*)&smP[w][q * 64 + (eo >> 1)];
        acc_l[mq] = __builtin_amdgcn_mfma_f32_16x16x32_bf16(ap[mq], vones, acc_l[mq], 0, 0, 0);
      }
      #pragma unroll
      for (int df = 0; df < 4; df++) {
        int d = df * 16 + lr;
        int eo = (ks * 64 + g * 16) ^ ((d & 7) << 4);
        short8 bv = *(const short8*)&V_[d * 64 + (eo >> 1)];
        #pragma unroll
        for (int mq = 0; mq < 2; mq++)
          acc_o[mq][df] = __builtin_amdgcn_mfma_f32_16x16x32_bf16(ap[mq], bv, acc_o[mq][df], 0, 0, 0);
      }
    }
    __builtin_amdgcn_s_setprio(0);
  };

  int cur = 0;
  for (int t = 0; t + 2 < 32; ++t) {
    asm volatile("s_waitcnt vmcnt(2)" ::: "memory");
    __builtin_amdgcn_sched_barrier(0);
    __builtin_amdgcn_s_barrier();
    __builtin_amdgcn_sched_barrier(0);
    int nb = (cur == 0) ? 2 : cur - 1;
    stage(nb, (t + 2) * 64);
    compute(cur);
    asm volatile("s_waitcnt lgkmcnt(0)" ::: "memory");
    __builtin_amdgcn_sched_barrier(0);
    cur = (cur == 2) ? 0 : cur + 1;
  }
  asm volatile("s_waitcnt vmcnt(2)" ::: "memory");
  __builtin_amdgcn_sched_barrier(0);
  __builtin_amdgcn_s_barrier();
  __builtin_amdgcn_sched_barrier(0);
  compute(cur);
  asm volatile("s_waitcnt lgkmcnt(0)" ::: "memory");
  __builtin_amdgcn_sched_barrier(0);
  cur = (cur == 2) ? 0 : cur + 1;
  asm volatile("s_waitcnt vmcnt(0)" ::: "memory");
  __builtin_amdgcn_sched_barrier(0);
  __builtin_amdgcn_s_barrier();
  __builtin_amdgcn_sched_barrier(0);
  compute(cur);

  #pragma unroll
  for (int mq = 0; mq < 2; mq++)
    #pragma unroll
    for (int j = 0; j < 4; j++) {
      float inv = 1.0f / acc_l[mq][j];
      #pragma unroll
      for (int df = 0; df < 4; df++) {
        int row = b * 2048 + q0 + mq * 16 + g * 4 + j;
        int col = h * 64 + df * 16 + lr;
        O[(size_t)row * 1024 + col] = f2bf(acc_o[mq][df][j] * inv);
      }
    }
}

// -------------------------------------------------------------------------
extern "C" void kernel_launch(void* const* d_in, const int* in_sizes, int n_in,
                              void* d_out, int out_size, void* d_ws, size_t ws_size,
                              hipStream_t stream) {
  const float* X  = (const float*)d_in[0];
  const float* Wq = (const float*)d_in[1];
  const float* Wk = (const float*)d_in[2];
  const float* Wv = (const float*)d_in[3];
  const float* Wo = (const float*)d_in[4];
  const float* bo = (const float*)d_in[5];
  const float* qd = (const float*)d_in[6];
  const float* qu = (const float*)d_in[7];
  const float* kd = (const float*)d_in[8];
  const float* ku = (const float*)d_in[9];
  const float* vd = (const float*)d_in[10];
  const float* vu = (const float*)d_in[11];
  const float* od = (const float*)d_in[12];
  const float* ou = (const float*)d_in[13];

  char* ws = (char*)d_ws;
  unsigned short* Wqkv = (unsigned short*)(ws);                       // 6,291,456 B
  unsigned short* Wob  = (unsigned short*)(ws + 6291456);             // 2,097,152 B
  unsigned short* Xb   = (unsigned short*)(ws + 8388608);             // 16,777,216 B (reused as attn out)
  unsigned short* QKV  = (unsigned short*)(ws + 25165824);            // 50,331,648 B (Q live)
  unsigned short* Kswz = (unsigned short*)(ws + 75497472);            // 16,777,216 B
  unsigned short* VTs  = (unsigned short*)(ws + 92274688);            // 16,777,216 B

  prep_in<<<12288, 256, 0, stream>>>(X, Xb, Wq, Wk, Wv, Wo, qd, qu, kd, ku,
                                     vd, vu, od, ou, Wqkv, Wob);
  // grid: x = m-tiles (64), y = n-tiles (24) -> per-XCD A-panel residency
  gemm_bt<0><<<dim3(64, 24), 256, 0, stream>>>(Xb, Wqkv, QKV, nullptr, nullptr,
                                               Kswz, VTs, 8192, 3072, 1024);
  attn<<<dim3(64, 8), 512, 0, stream>>>(QKV, Kswz, VTs, Xb);
  gemm_bt<1><<<dim3(64, 8), 256, 0, stream>>>(Xb, Wob, nullptr, (float*)d_out, bo,
                                              nullptr, nullptr, 8192, 1024, 1024);
}

// Round 17
// 179.764 us; speedup vs baseline: 1.0801x; 1.0801x over previous
//
#include <hip/hip_runtime.h>
#include <stdint.h>

typedef __attribute__((ext_vector_type(8))) short short8;
typedef __attribute__((ext_vector_type(4))) float f32x4;

typedef const unsigned int __attribute__((address_space(1))) gu32;
typedef unsigned int __attribute__((address_space(3))) lu32;

__device__ __forceinline__ float bf2f(unsigned short u) {
  union { unsigned int i; float f; } v; v.i = ((unsigned int)u) << 16; return v.f;
}
__device__ __forceinline__ unsigned short f2bf(float f) {
  union { float f; unsigned int i; } v; v.f = f;
  unsigned int r = v.i + 0x7FFFu + ((v.i >> 16) & 1u);
  return (unsigned short)(r >> 16);
}
__device__ __forceinline__ float fexp2(float x) {
  float r; asm("v_exp_f32 %0, %1" : "=v"(r) : "v"(x)); return r;
}
__device__ __forceinline__ unsigned int cvtpk(float lo, float hi) {
  unsigned int r;
  asm("v_cvt_pk_bf16_f32 %0, %1, %2" : "=v"(r) : "v"(lo), "v"(hi));
  return r;
}

// ------- fused: cast X fp32->bf16 (blocks 0..8191) + fold LoRA (8192..) ---
__global__ __launch_bounds__(256) void prep_in(
    const float* __restrict__ X, unsigned short* __restrict__ Xb,
    const float* __restrict__ Wq, const float* __restrict__ Wk,
    const float* __restrict__ Wv, const float* __restrict__ Wo,
    const float* __restrict__ qd, const float* __restrict__ qu,
    const float* __restrict__ kd, const float* __restrict__ ku,
    const float* __restrict__ vd, const float* __restrict__ vu,
    const float* __restrict__ od, const float* __restrict__ ou,
    unsigned short* __restrict__ Wqkv, unsigned short* __restrict__ Wob)
{
  if (blockIdx.x < 8192) {
    int i = (blockIdx.x * 256 + threadIdx.x) * 4;
    float4 v = *(const float4*)&X[i];
    unsigned long long pk = (unsigned long long)f2bf(v.x) |
                            ((unsigned long long)f2bf(v.y) << 16) |
                            ((unsigned long long)f2bf(v.z) << 32) |
                            ((unsigned long long)f2bf(v.w) << 48);
    *(unsigned long long*)&Xb[i] = pk;
    return;
  }
  int idx = (blockIdx.x - 8192) * 256 + threadIdx.x;
  int sel = idx >> 18;
  int rem = (idx & 0x3FFFF) * 4;
  int o = rem >> 10, c = rem & 1023;
  const float *W, *up, *dn;
  if (sel == 0)      { W = Wq; up = qu; dn = qd; }
  else if (sel == 1) { W = Wk; up = ku; dn = kd; }
  else if (sel == 2) { W = Wv; up = vu; dn = vd; }
  else               { W = Wo; up = ou; dn = od; }
  float4 wv = *(const float4*)&W[rem];
  float a0 = wv.x, a1 = wv.y, a2 = wv.z, a3 = wv.w;
  #pragma unroll
  for (int r = 0; r < 4; r++) {
    float u = up[o * 4 + r];
    float4 dv = *(const float4*)&dn[r * 1024 + c];
    a0 += u * dv.x; a1 += u * dv.y; a2 += u * dv.z; a3 += u * dv.w;
  }
  unsigned long long pk = (unsigned long long)f2bf(a0) |
                          ((unsigned long long)f2bf(a1) << 16) |
                          ((unsigned long long)f2bf(a2) << 32) |
                          ((unsigned long long)f2bf(a3) << 48);
  if (sel < 3) *(unsigned long long*)&Wqkv[sel * 1048576 + rem] = pk;
  else         *(unsigned long long*)&Wob[rem] = pk;
}

// ---------------- bf16 GEMM, B^T input (C[m,n] = sum_k A[m,k]*B[n,k]) ----
// 128x128 tile, BK=32, 4 waves, 256 thr. 3-slot LDS rotation, counted
// vmcnt(4), vmcnt before barrier, lgkmcnt(0) read-pin. Grid x=m, y=n
// (per-XCD A-panel L2 residency).
// OUTF=0 (QKV): LDS-repack epilogue, vbuf stride 148 shorts (296B == 10
// banks mod 32 -> conflict-free writes, <=4-way reads). Q -> QKV linear;
// K -> Kswz (16B-chunk XOR); V -> VTs transpose.
// OUTF=1: fp32 out + bias, DIRECT stores (R16 showed LDS-route regresses).
template <int OUTF>
__global__ __launch_bounds__(256) void gemm_bt(
    const unsigned short* __restrict__ A, const unsigned short* __restrict__ B,
    unsigned short* __restrict__ Cb, float* __restrict__ Cf,
    const float* __restrict__ bias, unsigned short* __restrict__ Kswz,
    unsigned short* __restrict__ VTs, int M, int N, int K)
{
  __shared__ unsigned short sm[24576];          // 48KB: 3xA(12288) + 3xB(12288)
  unsigned short* smA = sm;                     // [3][128*32]
  unsigned short* smB = sm + 12288;             // [3][128*32]
  const int tid = threadIdx.x;
  const int w = tid >> 6, lane = tid & 63;
  const int g = lane >> 4, lr = lane & 15;
  const int m0 = blockIdx.x * 128, n0 = blockIdx.y * 128;   // x=m, y=n
  const int srow = lane >> 2;
  const int scol = (lane & 3) * 8;
  const unsigned short* gA = A + (size_t)(m0 + w * 16 + srow) * K + scol;
  const unsigned short* gB = B + (size_t)(n0 + w * 16 + srow) * K + scol;
  f32x4 acc[4][4] = {};
  const int wr = (w >> 1) * 64, wc = (w & 1) * 64;

  auto stage = [&](int buf, int k0) {
    #pragma unroll
    for (int i = 0; i < 2; i++) {
      __builtin_amdgcn_global_load_lds((gu32*)(gA + (size_t)i * 64 * K + k0),
          (lu32*)&smA[buf * 4096 + (i * 64 + w * 16) * 32], 16, 0, 0);
      __builtin_amdgcn_global_load_lds((gu32*)(gB + (size_t)i * 64 * K + k0),
          (lu32*)&smB[buf * 4096 + (i * 64 + w * 16) * 32], 16, 0, 0);
    }
  };
  auto compute = [&](int buf) {
    short8 a[4], b[4];
    #pragma unroll
    for (int mi = 0; mi < 4; mi++) a[mi] = *(const short8*)&smA[buf * 4096 + (wr + mi * 16 + lr) * 32 + g * 8];
    #pragma unroll
    for (int ni = 0; ni < 4; ni++) b[ni] = *(const short8*)&smB[buf * 4096 + (wc + ni * 16 + lr) * 32 + g * 8];
    #pragma unroll
    for (int mi = 0; mi < 4; mi++)
      #pragma unroll
      for (int ni = 0; ni < 4; ni++)
        acc[mi][ni] = __builtin_amdgcn_mfma_f32_16x16x32_bf16(a[mi], b[ni], acc[mi][ni], 0, 0, 0);
  };

  const int nt = K / 32;                 // >= 3
  stage(0, 0);
  stage(1, 32);
  int cur = 0;
  for (int t = 0; t + 2 < nt; ++t) {
    asm volatile("s_waitcnt vmcnt(4)" ::: "memory");   // stage(t) landed
    __builtin_amdgcn_sched_barrier(0);
    __builtin_amdgcn_s_barrier();
    __builtin_amdgcn_sched_barrier(0);
    int nb = (cur == 0) ? 2 : cur - 1;                 // (cur+2)%3
    stage(nb, (t + 2) * 32);
    compute(cur);
    asm volatile("s_waitcnt lgkmcnt(0)" ::: "memory"); // pin ds_reads before next barrier
    __builtin_amdgcn_sched_barrier(0);
    cur = (cur == 2) ? 0 : cur + 1;
  }
  asm volatile("s_waitcnt vmcnt(4)" ::: "memory");
  __builtin_amdgcn_sched_barrier(0);
  __builtin_amdgcn_s_barrier();
  __builtin_amdgcn_sched_barrier(0);
  compute(cur);
  asm volatile("s_waitcnt lgkmcnt(0)" ::: "memory");
  __builtin_amdgcn_sched_barrier(0);
  cur = (cur == 2) ? 0 : cur + 1;
  asm volatile("s_waitcnt vmcnt(0)" ::: "memory");     // all stages landed
  __builtin_amdgcn_sched_barrier(0);
  __builtin_amdgcn_s_barrier();
  __builtin_amdgcn_sched_barrier(0);
  compute(cur);

  if (OUTF == 1) {
    #pragma unroll
    for (int mi = 0; mi < 4; mi++)
      #pragma unroll
      for (int ni = 0; ni < 4; ni++) {
        int col = n0 + wc + ni * 16 + lr;
        #pragma unroll
        for (int j = 0; j < 4; j++) {
          int row = m0 + wr + mi * 16 + g * 4 + j;
          Cf[(size_t)row * N + col] = acc[mi][ni][j] + bias[col];
        }
      }
    return;
  }

  // ---- unified LDS-repack epilogue (all global_load_lds drained above) ----
  __syncthreads();                                   // all compute ds_reads done
  unsigned short* vbuf = sm;                         // [128][148]: 37,888B
  #pragma unroll
  for (int mi = 0; mi < 4; mi++)
    #pragma unroll
    for (int ni = 0; ni < 4; ni++)
      #pragma unroll
      for (int j = 0; j < 4; j++)
        vbuf[(wr + mi * 16 + g * 4 + j) * 148 + wc + ni * 16 + lr] =
            f2bf(acc[mi][ni][j]);
  __syncthreads();

  if (n0 < 1024) {
    // Q -> QKV rows (full 16B-coalesced)
    int r = tid >> 1, hf = tid & 1;
    unsigned short* dst = Cb + (size_t)(m0 + r) * 3072 + n0 + hf * 64;
    #pragma unroll
    for (int j = 0; j < 8; j++)
      *(short8*)&dst[j * 8] = *(const short8*)&vbuf[r * 148 + hf * 64 + j * 8];
  } else if (n0 < 2048) {
    // K -> Kswz: 16B-chunk XOR within the 128B row (d^((s&7)<<3) == chunk^sw)
    int r = tid >> 1, hf = tid & 1;
    int sg = m0 + r, b_ = sg >> 11, s = sg & 2047;
    int h = (n0 - 1024 + hf * 64) >> 6;
    size_t base = ((size_t)(b_ * 16 + h) * 2048 + s) * 64;
    int sw = s & 7;
    #pragma unroll
    for (int gch = 0; gch < 8; gch++)
      *(short8*)&Kswz[base + (gch ^ sw) * 8] =
          *(const short8*)&vbuf[r * 148 + hf * 64 + gch * 8];
  } else {
    // V -> VTs transpose (R14-proven algebra)
    int b_ = m0 >> 11, s0g = m0 & 2047;
    int ck0 = n0 - 2048;
    int dd = tid >> 1, shalf = tid & 1;              // dd: tile col 0..127
    int d = dd & 63, h = (ck0 >> 6) + (dd >> 6);
    size_t rowbase = ((size_t)(b_ * 16 + h) * 64 + d) * 2048;
    #pragma unroll
    for (int gp = 0; gp < 8; gp++) {
      int gs = gp ^ (d & 7);
      short8 o;
      #pragma unroll
      for (int j = 0; j < 8; j++)
        o[j] = (short)vbuf[(shalf * 64 + gs * 8 + j) * 148 + dd];
      *(short8*)&VTs[rowbase + s0g + shalf * 64 + gp * 8] = o;
    }
  }
}

// ---------------- flash attention, bf16, swapped QK^T (16x16) ------------
// grid: (64 bh, 8 q-blocks of 256); all q-blocks of one bh on one XCD.
__global__ __launch_bounds__(512, 4) void attn(
    const unsigned short* __restrict__ QKV,
    const unsigned short* __restrict__ Kswz,
    const unsigned short* __restrict__ VTs,
    unsigned short* __restrict__ O)
{
  __shared__ unsigned short smK[3][64 * 64];
  __shared__ unsigned short smV[3][64 * 64];
  __shared__ unsigned short smP[8][32 * 64];
  int bh = blockIdx.x, qb = blockIdx.y;
  int b = bh >> 4, h = bh & 15;
  int tid = threadIdx.x, w = tid >> 6, lane = tid & 63;
  int g = lane >> 4, lr = lane & 15;
  int q0 = qb * 256 + w * 32;
  const size_t kbse = (size_t)bh * 2048 * 64;
  const size_t vbse = (size_t)bh * 64 * 2048;
  const int srow8 = lane >> 3;
  const int sc8 = (lane & 7) * 8;

  auto stage = [&](int buf, int n0) {
    const unsigned short* gk = &Kswz[kbse + (size_t)(n0 + w * 8 + srow8) * 64 + sc8];
    __builtin_amdgcn_global_load_lds((gu32*)gk, (lu32*)&smK[buf][(w * 8) * 64], 16, 0, 0);
    const unsigned short* gv = &VTs[vbse + (size_t)(w * 8 + srow8) * 2048 + n0 + sc8];
    __builtin_amdgcn_global_load_lds((gu32*)gv, (lu32*)&smV[buf][(w * 8) * 64], 16, 0, 0);
  };

  const float SC = 0.125f * 1.44269504f;
  short8 bq[2][2];
  #pragma unroll
  for (int qf = 0; qf < 2; qf++)
    #pragma unroll
    for (int ks = 0; ks < 2; ks++) {
      short8 v = *(const short8*)&QKV[(size_t)(b * 2048 + q0 + qf * 16 + lr) * 3072 +
                                      h * 64 + ks * 32 + g * 8];
      #pragma unroll
      for (int j = 0; j < 4; j++) {
        float f0 = bf2f((unsigned short)v[2 * j]) * SC;
        float f1 = bf2f((unsigned short)v[2 * j + 1]) * SC;
        ((unsigned int*)&v)[j] = cvtpk(f0, f1);
      }
      bq[qf][ks] = v;
    }

  short8 vones;
  #pragma unroll
  for (int j = 0; j < 8; j++) vones[j] = (short)0x3F80;

  f32x4 acc_o[2][4] = {};
  f32x4 acc_l[2] = {};

  asm volatile("s_waitcnt vmcnt(0)" ::: "memory");
  __builtin_amdgcn_sched_barrier(0);
  stage(0, 0);
  stage(1, 64);

  auto compute = [&](int buf) {
    const unsigned short* K_ = smK[buf];
    const unsigned short* V_ = smV[buf];
    f32x4 s[4][2] = {};
    __builtin_amdgcn_s_setprio(1);
    #pragma unroll
    for (int nf = 0; nf < 4; nf++) {
      int row = nf * 16 + lr;
      #pragma unroll
      for (int ks = 0; ks < 2; ks++) {
        int eo = (ks * 64 + g * 16) ^ ((row & 7) << 4);
        short8 ak = *(const short8*)&K_[row * 64 + (eo >> 1)];
        #pragma unroll
        for (int qf = 0; qf < 2; qf++)
          s[nf][qf] = __builtin_amdgcn_mfma_f32_16x16x32_bf16(ak, bq[qf][ks], s[nf][qf], 0, 0, 0);
      }
    }
    __builtin_amdgcn_s_setprio(0);

    #pragma unroll
    for (int qf = 0; qf < 2; qf++) {
      int q = qf * 16 + lr;
      #pragma unroll
      for (int nf = 0; nf < 4; nf++) {
        float p0 = fexp2(s[nf][qf][0]);
        float p1 = fexp2(s[nf][qf][1]);
        float p2 = fexp2(s[nf][qf][2]);
        float p3 = fexp2(s[nf][qf][3]);
        uint2 pw;
        pw.x = cvtpk(p0, p1);
        pw.y = cvtpk(p2, p3);
        int eo = ((nf * 16 + g * 4) * 2) ^ ((q & 7) << 4);
        *(uint2*)&smP[w][q * 64 + (eo >> 1)] = pw;
      }
    }

    __builtin_amdgcn_s_setprio(1);
    #pragma unroll
    for (int ks = 0; ks < 2; ks++) {
      short8 ap[2];
      #pragma unroll
      for (int mq = 0; mq < 2; mq++) {
        int q = mq * 16 + lr;
        int eo = (ks * 64 + g * 16) ^ ((q & 7) << 4);
        ap[mq] = *(const short8*)&smP[w][q * 64 + (eo >> 1)];
        acc_l[mq] = __builtin_amdgcn_mfma_f32_16x16x32_bf16(ap[mq], vones, acc_l[mq], 0, 0, 0);
      }
      #pragma unroll
      for (int df = 0; df < 4; df++) {
        int d = df * 16 + lr;
        int eo = (ks * 64 + g * 16) ^ ((d & 7) << 4);
        short8 bv = *(const short8*)&V_[d * 64 + (eo >> 1)];
        #pragma unroll
        for (int mq = 0; mq < 2; mq++)
          acc_o[mq][df] = __builtin_amdgcn_mfma_f32_16x16x32_bf16(ap[mq], bv, acc_o[mq][df], 0, 0, 0);
      }
    }
    __builtin_amdgcn_s_setprio(0);
  };

  int cur = 0;
  for (int t = 0; t + 2 < 32; ++t) {
    asm volatile("s_waitcnt vmcnt(2)" ::: "memory");
    __builtin_amdgcn_sched_barrier(0);
    __builtin_amdgcn_s_barrier();
    __builtin_amdgcn_sched_barrier(0);
    int nb = (cur == 0) ? 2 : cur - 1;
    stage(nb, (t + 2) * 64);
    compute(cur);
    asm volatile("s_waitcnt lgkmcnt(0)" ::: "memory");
    __builtin_amdgcn_sched_barrier(0);
    cur = (cur == 2) ? 0 : cur + 1;
  }
  asm volatile("s_waitcnt vmcnt(2)" ::: "memory");
  __builtin_amdgcn_sched_barrier(0);
  __builtin_amdgcn_s_barrier();
  __builtin_amdgcn_sched_barrier(0);
  compute(cur);
  asm volatile("s_waitcnt lgkmcnt(0)" ::: "memory");
  __builtin_amdgcn_sched_barrier(0);
  cur = (cur == 2) ? 0 : cur + 1;
  asm volatile("s_waitcnt vmcnt(0)" ::: "memory");
  __builtin_amdgcn_sched_barrier(0);
  __builtin_amdgcn_s_barrier();
  __builtin_amdgcn_sched_barrier(0);
  compute(cur);

  #pragma unroll
  for (int mq = 0; mq < 2; mq++)
    #pragma unroll
    for (int j = 0; j < 4; j++) {
      float inv = 1.0f / acc_l[mq][j];
      #pragma unroll
      for (int df = 0; df < 4; df++) {
        int row = b * 2048 + q0 + mq * 16 + g * 4 + j;
        int col = h * 64 + df * 16 + lr;
        O[(size_t)row * 1024 + col] = f2bf(acc_o[mq][df][j] * inv);
      }
    }
}

// -------------------------------------------------------------------------
extern "C" void kernel_launch(void* const* d_in, const int* in_sizes, int n_in,
                              void* d_out, int out_size, void* d_ws, size_t ws_size,
                              hipStream_t stream) {
  const float* X  = (const float*)d_in[0];
  const float* Wq = (const float*)d_in[1];
  const float* Wk = (const float*)d_in[2];
  const float* Wv = (const float*)d_in[3];
  const float* Wo = (const float*)d_in[4];
  const float* bo = (const float*)d_in[5];
  const float* qd = (const float*)d_in[6];
  const float* qu = (const float*)d_in[7];
  const float* kd = (const float*)d_in[8];
  const float* ku = (const float*)d_in[9];
  const float* vd = (const float*)d_in[10];
  const float* vu = (const float*)d_in[11];
  const float* od = (const float*)d_in[12];
  const float* ou = (const float*)d_in[13];

  char* ws = (char*)d_ws;
  unsigned short* Wqkv = (unsigned short*)(ws);                       // 6,291,456 B
  unsigned short* Wob  = (unsigned short*)(ws + 6291456);             // 2,097,152 B
  unsigned short* Xb   = (unsigned short*)(ws + 8388608);             // 16,777,216 B (reused as attn out)
  unsigned short* QKV  = (unsigned short*)(ws + 25165824);            // 50,331,648 B (Q live)
  unsigned short* Kswz = (unsigned short*)(ws + 75497472);            // 16,777,216 B
  unsigned short* VTs  = (unsigned short*)(ws + 92274688);            // 16,777,216 B

  prep_in<<<12288, 256, 0, stream>>>(X, Xb, Wq, Wk, Wv, Wo, qd, qu, kd, ku,
                                     vd, vu, od, ou, Wqkv, Wob);
  // grid: x = m-tiles (64), y = n-tiles (24) -> per-XCD A-panel residency
  gemm_bt<0><<<dim3(64, 24), 256, 0, stream>>>(Xb, Wqkv, QKV, nullptr, nullptr,
                                               Kswz, VTs, 8192, 3072, 1024);
  attn<<<dim3(64, 8), 512, 0, stream>>>(QKV, Kswz, VTs, Xb);
  gemm_bt<1><<<dim3(64, 8), 256, 0, stream>>>(Xb, Wob, nullptr, (float*)d_out, bo,
                                              nullptr, nullptr, 8192, 1024, 1024);
}